// Round 17
// baseline (5034.612 us; speedup 1.0000x reference)
//
// ViT-Base/16 fwd + JVP — Round 16: R15 base + GELU derivative cached in dead
// accf registers (halves epilogue gelu VALU; was computed twice per element),
// rcp for softmax reciprocal.
#include <hip/hip_runtime.h>
#include <math.h>

static constexpr int B_   = 32;
static constexpr int S_   = 197;
static constexpr int D_   = 768;
static constexpr int H_   = 12;
static constexpr int L_   = 12;
static constexpr int MD_  = 3072;
static constexpr int NC_  = 1000;
static constexpr int GP_  = 196;
static constexpr int KP_  = 224;
static constexpr int MP_  = 6400;
static constexpr int EPAD = 136;   // staged bf16 epilogue LDS row stride (shorts)

typedef __attribute__((ext_vector_type(8))) short bf16x8v;
typedef __attribute__((ext_vector_type(4))) float f32x4v;

__device__ __forceinline__ unsigned short f2bf(float x) {
    union { float f; unsigned u; } v; v.f = x;
    unsigned r = v.u + 0x7fffu + ((v.u >> 16) & 1u);   // RNE
    return (unsigned short)(r >> 16);
}

// fast tanh-form GELU + derivative (|err| vs exact erf-GELU ~3e-4)
__device__ __forceinline__ void gelu_pair(float u, float& val, float& dcoef) {
    const float u2 = u * u;
    const float inner = 0.7978845608028654f * u * (1.f + 0.044715f * u2);
    const float e2 = __expf(2.f * inner);
    const float t = 1.f - 2.f * __builtin_amdgcn_rcpf(e2 + 1.f);
    val = 0.5f * u * (1.f + t);
    const float dinner = 0.7978845608028654f * (1.f + 0.134145f * u2);
    dcoef = 0.5f * (1.f + t) + 0.5f * u * (1.f - t * t) * dinner;
}

#define GLOAD_LDS16(gptr, lptr) \
    __builtin_amdgcn_global_load_lds((const __attribute__((address_space(1))) void*)(gptr), \
        (__attribute__((address_space(3))) void*)(lptr), 16, 0, 0)

__device__ __forceinline__ void xcd_swizzle(int& bx, int& by) {
    const int gx = gridDim.x, nwg = gx * gridDim.y;
    const int flat = blockIdx.y * gx + blockIdx.x;
    const int q = nwg >> 3, r = nwg & 7;
    const int xcd = flat & 7, idx = flat >> 3;
    const int nf = (xcd < r ? xcd * (q + 1) : r * (q + 1) + (xcd - r) * q) + idx;
    bx = nf % gx; by = nf / gx;
}

// ============ paired MFMA GEMM: 64x128 block tile, 4 waves (2x2), wave 32x64 ============
// MODE: 0 fp32 store, 1 fp32 ACC (staged coalesced RMW), 2 bf16 store, 3 GELU-JVP -> bf16.
template<int MODE, bool BIAS>
__global__ __launch_bounds__(256, 4) void mfma_pair_kernel(
    const short* __restrict__ Af, const short* __restrict__ At,
    const short* __restrict__ Bm, const float* __restrict__ bias,
    void* __restrict__ Cfv, void* __restrict__ Ctv,
    int Mhalf, int N, int K, int ldc)
{
    int bx, by; xcd_swizzle(bx, by);
    __shared__ __align__(16) short lds[16384];   // 32 KB
    const int tid  = threadIdx.x;
    const int lane = tid & 63;
    const int w    = tid >> 6;
    const int m0 = by * 64, n0 = bx * 128;
    const int wr = w >> 1, wc = w & 1;
    f32x4v accf[2][4] = {}, acct[2][4] = {};

    const int r_in = lane >> 2;
    const int cdst = lane & 3;
    const int sa = w * 16 + r_in;
    const int csa = cdst ^ ((sa >> 1) & 3);
    const size_t aoff = (size_t)(m0 + sa) * K + csa * 8;
    const int sb0 = w * 32 + r_in;
    const int sb1 = w * 32 + 16 + r_in;
    const int csb0 = cdst ^ ((sb0 >> 1) & 3);
    const int csb1 = cdst ^ ((sb1 >> 1) & 3);
    const size_t boff0 = (size_t)(n0 + sb0) * K + csb0 * 8;
    const size_t boff1 = (size_t)(n0 + sb1) * K + csb1 * 8;

#define LAF(b) (&lds[(b) * 2048])
#define LAT(b) (&lds[4096 + (b) * 2048])
#define LBB(b) (&lds[8192 + (b) * 4096])
#define STAGE(buf, koff) do {                                         \
        GLOAD_LDS16(Af + aoff  + (koff), LAF(buf) + w * 512);         \
        GLOAD_LDS16(At + aoff  + (koff), LAT(buf) + w * 512);         \
        GLOAD_LDS16(Bm + boff0 + (koff), LBB(buf) + w * 1024);        \
        GLOAD_LDS16(Bm + boff1 + (koff), LBB(buf) + w * 1024 + 512);  \
    } while (0)

    STAGE(0, 0);
    __syncthreads();

    const int NSTEP = K >> 5;
    int cur = 0;
    for (int k = 0; k < NSTEP; ++k) {
        const int nxt = cur ^ 1;
        if (k + 1 < NSTEP) STAGE(nxt, (size_t)(k + 1) * 32);
        bf16x8v af[2], at[2], bfr[4];
        #pragma unroll
        for (int m = 0; m < 2; ++m) {
            const int row = wr * 32 + m * 16 + (lane & 15);
            const int c = (lane >> 4) ^ ((row >> 1) & 3);
            af[m] = *(const bf16x8v*)(LAF(cur) + row * 32 + c * 8);
            at[m] = *(const bf16x8v*)(LAT(cur) + row * 32 + c * 8);
        }
        #pragma unroll
        for (int n = 0; n < 4; ++n) {
            const int row = wc * 64 + n * 16 + (lane & 15);
            const int c = (lane >> 4) ^ ((row >> 1) & 3);
            bfr[n] = *(const bf16x8v*)(LBB(cur) + row * 32 + c * 8);
        }
        #pragma unroll
        for (int m = 0; m < 2; ++m)
            #pragma unroll
            for (int n = 0; n < 4; ++n) {
                accf[m][n] = __builtin_amdgcn_mfma_f32_16x16x32_bf16(af[m], bfr[n], accf[m][n], 0, 0, 0);
                acct[m][n] = __builtin_amdgcn_mfma_f32_16x16x32_bf16(at[m], bfr[n], acct[m][n], 0, 0, 0);
            }
        __syncthreads();
        cur = nxt;
    }
#undef STAGE
#undef LAF
#undef LAT
#undef LBB

    const int g2 = lane >> 4, kc = lane & 15;
    if (MODE == 0) {
        const int col_base = n0 + wc * 64 + kc;
        const int row_base = m0 + wr * 32 + g2 * 4;
        #pragma unroll
        for (int n = 0; n < 4; ++n) {
            const int col = col_base + n * 16;
            const float bv = BIAS ? bias[col] : 0.f;
            #pragma unroll
            for (int m = 0; m < 2; ++m) {
                const int row = row_base + m * 16;
                #pragma unroll
                for (int r = 0; r < 4; ++r) {
                    if (row + r < Mhalf) {
                        const size_t off = (size_t)(row + r) * ldc + col;
                        ((float*)Cfv)[off] = accf[m][n][r] + bv;
                        ((float*)Ctv)[off] = acct[m][n][r];
                    }
                }
            }
        }
    } else if (MODE == 1) {
        // staged fp32 ACC: LDS [64][128] with col-XOR swizzle, coalesced float4 RMW
        float* lf = (float*)lds;
        #pragma unroll
        for (int half = 0; half < 2; ++half) {
            #pragma unroll
            for (int n = 0; n < 4; ++n) {
                const int col = wc * 64 + n * 16 + kc;
                const float bv = BIAS ? bias[n0 + col] : 0.f;
                #pragma unroll
                for (int m = 0; m < 2; ++m) {
                    #pragma unroll
                    for (int r = 0; r < 4; ++r) {
                        const int row = wr * 32 + m * 16 + g2 * 4 + r;
                        const int swz = ((row >> 2) & 3) << 4;
                        lf[row * 128 + (col ^ swz)] =
                            half == 0 ? (accf[m][n][r] + bv) : acct[m][n][r];
                    }
                }
            }
            __syncthreads();
            float* dst = (float*)(half == 0 ? Cfv : Ctv);
            #pragma unroll
            for (int it = 0; it < 4; ++it) {
                const int row = it * 16 + (tid >> 4);
                const int grow = m0 + row;
                const int swz = ((row >> 2) & 3) << 4;
                if (grow < Mhalf) {
                    #pragma unroll
                    for (int q = 0; q < 2; ++q) {
                        const int c4 = (tid & 15) * 8 + q * 4;
                        float* gp = dst + (size_t)grow * ldc + n0 + c4;
                        float4 g = *(float4*)gp;
                        const float4 s = *(const float4*)&lf[row * 128 + (c4 ^ swz)];
                        g.x += s.x; g.y += s.y; g.z += s.z; g.w += s.w;
                        *(float4*)gp = g;
                    }
                }
            }
            __syncthreads();
        }
    } else {
        // staged bf16 epilogue (stride EPAD), coalesced flush.
        // MODE 3: half 0 computes gelu value AND caches derivative into the
        // (dead) accf registers; half 1 just multiplies — no recompute.
        #pragma unroll
        for (int half = 0; half < 2; ++half) {
            #pragma unroll
            for (int n = 0; n < 4; ++n) {
                const int col = wc * 64 + n * 16 + kc;
                const float bv = BIAS ? bias[n0 + col] : 0.f;
                #pragma unroll
                for (int m = 0; m < 2; ++m) {
                    #pragma unroll
                    for (int r = 0; r < 4; ++r) {
                        const int row = wr * 32 + m * 16 + g2 * 4 + r;
                        float outv;
                        if (MODE == 2) {
                            outv = half == 0 ? (accf[m][n][r] + bv) : acct[m][n][r];
                        } else {
                            if (half == 0) {
                                float gv, gd;
                                gelu_pair(accf[m][n][r] + bv, gv, gd);
                                outv = gv;
                                accf[m][n][r] = gd;     // cache derivative
                            } else {
                                outv = acct[m][n][r] * accf[m][n][r];
                            }
                        }
                        lds[row * EPAD + col] = (short)f2bf(outv);
                    }
                }
            }
            __syncthreads();
            short* dst = (short*)(half == 0 ? Cfv : Ctv);
            #pragma unroll
            for (int it = 0; it < 4; ++it) {
                const int row = it * 16 + (tid >> 4);
                const int grow = m0 + row;
                if (grow < Mhalf) {
                    *(bf16x8v*)(dst + (size_t)grow * ldc + n0 + (tid & 15) * 8)
                        = *(const bf16x8v*)&lds[row * EPAD + (tid & 15) * 8];
                }
            }
            __syncthreads();
        }
    }
}

// ================= fully fused attention JVP =================
__global__ __launch_bounds__(256) void attn_fused_kernel(
    const short* __restrict__ qkvb, const short* __restrict__ dqkvb,
    const short* __restrict__ Vtb_, const short* __restrict__ dVtb_,
    short* __restrict__ obf, short* __restrict__ dobf)
{
    const int qt = blockIdx.x;
    const int b  = blockIdx.y;
    const int n = b / H_, h = b - n * H_;
    const short* qb  = qkvb  + (size_t)n * S_ * 2304 + h * 64;
    const short* kb  = qb + 768;
    const short* dqb = dqkvb + (size_t)n * S_ * 2304 + h * 64;
    const short* dkb = dqb + 768;
    const short* Vb  = Vtb_  + (size_t)b * 64 * KP_;
    const short* dVb = dVtb_ + (size_t)b * 64 * KP_;

    __shared__ __align__(16) short lds[32768];
    const int tid = threadIdx.x, lane = tid & 63, w = tid >> 6;
    const int g = lane >> 4, kc = lane & 15;
    const int srow = lane >> 2, cdst = lane & 3;
    const int csrc = cdst ^ ((srow >> 1) & 3);

    {
        const size_t qr = (size_t)min(qt * 64 + w * 16 + srow, S_ - 1) * 2304;
        #pragma unroll
        for (int kw = 0; kw < 2; ++kw) {
            GLOAD_LDS16(qb  + qr + kw * 32 + csrc * 8, &lds[w * 1024 + kw * 512]);
            GLOAD_LDS16(dqb + qr + kw * 32 + csrc * 8, &lds[4096 + w * 1024 + kw * 512]);
        }
    }

    f32x4v aS[14], aD[14];
    #pragma unroll
    for (int i = 0; i < 14; ++i) { aS[i] = (f32x4v){0,0,0,0}; aD[i] = (f32x4v){0,0,0,0}; }
    bf16x8v qf[2], dqf[2];

    #pragma unroll
    for (int kt = 0; kt < 7; ++kt) {
        {
            const int kwin = w & 1;
            const short* src = (w < 2) ? kb : dkb;
            const int base = (w < 2) ? 8192 : 10240;
            #pragma unroll
            for (int half = 0; half < 2; ++half) {
                const size_t kr = (size_t)min(kt * 32 + half * 16 + srow, S_ - 1) * 2304;
                GLOAD_LDS16(src + kr + kwin * 32 + csrc * 8,
                            &lds[base + kwin * 1024 + half * 512]);
            }
        }
        __syncthreads();
        if (kt == 0) {
            #pragma unroll
            for (int kw = 0; kw < 2; ++kw) {
                const int c = g ^ ((kc >> 1) & 3);
                qf[kw]  = *(const bf16x8v*)&lds[w * 1024 + kw * 512 + kc * 32 + c * 8];
                dqf[kw] = *(const bf16x8v*)&lds[4096 + w * 1024 + kw * 512 + kc * 32 + c * 8];
            }
        }
        #pragma unroll
        for (int nf = 0; nf < 2; ++nf) {
            const int row = nf * 16 + kc;
            const int c = g ^ ((row >> 1) & 3);
            const bf16x8v kf0  = *(const bf16x8v*)&lds[8192  + row * 32 + c * 8];
            const bf16x8v kf1  = *(const bf16x8v*)&lds[8192  + 1024 + row * 32 + c * 8];
            const bf16x8v dkf0 = *(const bf16x8v*)&lds[10240 + row * 32 + c * 8];
            const bf16x8v dkf1 = *(const bf16x8v*)&lds[10240 + 1024 + row * 32 + c * 8];
            const int fi = kt * 2 + nf;
            aS[fi] = __builtin_amdgcn_mfma_f32_16x16x32_bf16(qf[0], kf0, aS[fi], 0,0,0);
            aS[fi] = __builtin_amdgcn_mfma_f32_16x16x32_bf16(qf[1], kf1, aS[fi], 0,0,0);
            aD[fi] = __builtin_amdgcn_mfma_f32_16x16x32_bf16(dqf[0], kf0, aD[fi], 0,0,0);
            aD[fi] = __builtin_amdgcn_mfma_f32_16x16x32_bf16(dqf[1], kf1, aD[fi], 0,0,0);
            aD[fi] = __builtin_amdgcn_mfma_f32_16x16x32_bf16(qf[0], dkf0, aD[fi], 0,0,0);
            aD[fi] = __builtin_amdgcn_mfma_f32_16x16x32_bf16(qf[1], dkf1, aD[fi], 0,0,0);
        }
        __syncthreads();
    }

    float pm[4] = {-3.0e38f, -3.0e38f, -3.0e38f, -3.0e38f};
    #pragma unroll
    for (int fi = 0; fi < 14; ++fi) {
        if (fi * 16 + kc < S_) {
            #pragma unroll
            for (int r = 0; r < 4; ++r) pm[r] = fmaxf(pm[r], aS[fi][r]);
        }
    }
    #pragma unroll
    for (int off = 1; off < 16; off <<= 1)
        #pragma unroll
        for (int r = 0; r < 4; ++r) pm[r] = fmaxf(pm[r], __shfl_xor(pm[r], off));

    float den[4] = {0,0,0,0}, tsm[4] = {0,0,0,0};
    #pragma unroll
    for (int fi = 0; fi < 14; ++fi) {
        const bool val = fi * 16 + kc < S_;
        #pragma unroll
        for (int r = 0; r < 4; ++r) {
            const float s  = aS[fi][r] * 0.125f;
            const float ds = aD[fi][r] * 0.125f;
            const float e = val ? __expf(s - pm[r] * 0.125f) : 0.f;
            den[r] += e; tsm[r] += e * ds;
            aS[fi][r] = e; aD[fi][r] = ds;
        }
    }
    #pragma unroll
    for (int off = 1; off < 16; off <<= 1)
        #pragma unroll
        for (int r = 0; r < 4; ++r) {
            den[r] += __shfl_xor(den[r], off);
            tsm[r] += __shfl_xor(tsm[r], off);
        }
    float inv[4], tq[4];
    #pragma unroll
    for (int r = 0; r < 4; ++r) {
        inv[r] = __builtin_amdgcn_rcpf(den[r]);
        tq[r] = tsm[r] * inv[r];
    }

    const int lpw = w * 3584, ldpw = 14336 + w * 3584;
    #pragma unroll
    for (int fi = 0; fi < 14; ++fi) {
        const int kwin = fi >> 1;
        const int chunkbase = (fi & 1) * 2 + (kc >> 3);
        #pragma unroll
        for (int r = 0; r < 4; ++r) {
            const int qs = g * 4 + r;
            const int swz = chunkbase ^ ((qs >> 1) & 3);
            const int addr = kwin * 512 + qs * 32 + swz * 8 + (kc & 7);
            const float p  = aS[fi][r] * inv[r];
            const float dp = p * (aD[fi][r] - tq[r]);
            lds[lpw  + addr] = (short)f2bf(p);
            lds[ldpw + addr] = (short)f2bf(dp);
        }
    }

    f32x4v aO[4], aDO[4];
    #pragma unroll
    for (int i = 0; i < 4; ++i) { aO[i] = (f32x4v){0,0,0,0}; aDO[i] = (f32x4v){0,0,0,0}; }

    #pragma unroll
    for (int kt = 0; kt < 7; ++kt) {
        {
            const size_t vr = (size_t)(w * 16 + srow) * KP_ + kt * 32 + csrc * 8;
            GLOAD_LDS16(Vb  + vr, &lds[28672 + w * 512]);
            GLOAD_LDS16(dVb + vr, &lds[30720 + w * 512]);
        }
        __syncthreads();
        bf16x8v pa, dpa;
        {
            const int c = g ^ ((kc >> 1) & 3);
            pa  = *(const bf16x8v*)&lds[lpw  + kt * 512 + kc * 32 + c * 8];
            dpa = *(const bf16x8v*)&lds[ldpw + kt * 512 + kc * 32 + c * 8];
        }
        #pragma unroll
        for (int nf = 0; nf < 4; ++nf) {
            const int row = nf * 16 + kc;
            const int c = (g) ^ ((row >> 1) & 3);
            const bf16x8v vf  = *(const bf16x8v*)&lds[28672 + row * 32 + c * 8];
            const bf16x8v dvf = *(const bf16x8v*)&lds[30720 + row * 32 + c * 8];
            aO[nf]  = __builtin_amdgcn_mfma_f32_16x16x32_bf16(pa,  vf,  aO[nf], 0,0,0);
            aDO[nf] = __builtin_amdgcn_mfma_f32_16x16x32_bf16(dpa, vf,  aDO[nf], 0,0,0);
            aDO[nf] = __builtin_amdgcn_mfma_f32_16x16x32_bf16(pa,  dvf, aDO[nf], 0,0,0);
        }
        __syncthreads();
    }

    short* ob  = obf  + (size_t)n * S_ * D_ + h * 64;
    short* dob = dobf + (size_t)n * S_ * D_ + h * 64;
    #pragma unroll
    for (int nf = 0; nf < 4; ++nf) {
        const int dh = nf * 16 + kc;
        #pragma unroll
        for (int r = 0; r < 4; ++r) {
            const int q = qt * 64 + w * 16 + g * 4 + r;
            if (q < S_) {
                ob [(size_t)q * D_ + dh] = (short)f2bf(aO[nf][r]);
                dob[(size_t)q * D_ + dh] = (short)f2bf(aDO[nf][r]);
            }
        }
    }
}

// ================= V transpose =================
__global__ __launch_bounds__(256) void vtrans_kernel(
    const short* __restrict__ qkvb, const short* __restrict__ dqkvb,
    short* __restrict__ Vt, short* __restrict__ dVt)
{
    const int blk = blockIdx.x;
    const int b = blk >> 2, kt = blk & 3;
    const int n = b / H_, h = b - n * H_;
    const short* vb  = qkvb  + (size_t)n * S_ * 2304 + 1536 + h * 64;
    const short* dvb = dqkvb + (size_t)n * S_ * 2304 + 1536 + h * 64;
    __shared__ short t1[64][65], t2[64][65];
    const int tid = threadIdx.x;
    #pragma unroll
    for (int j = 0; j < 16; ++j) {
        const int e = tid + 256 * j;
        const int kk = e >> 6, dh = e & 63;
        const int gk = kt * 64 + kk;
        short v = 0, dv = 0;
        if (gk < S_) { v = vb[(size_t)gk * 2304 + dh]; dv = dvb[(size_t)gk * 2304 + dh]; }
        t1[dh][kk] = v; t2[dh][kk] = dv;
    }
    __syncthreads();
    #pragma unroll
    for (int j = 0; j < 16; ++j) {
        const int e = tid + 256 * j;
        const int dh = e >> 6, kk = e & 63;
        const int ok = kt * 64 + kk;
        if (ok < KP_) {
            Vt [(size_t)b * 64 * KP_ + (size_t)dh * KP_ + ok] = t1[dh][kk];
            dVt[(size_t)b * 64 * KP_ + (size_t)dh * KP_ + ok] = t2[dh][kk];
        }
    }
}

// ================= fp32 GEMM (head only) =================
template<bool BIAS>
__global__ __launch_bounds__(256) void gemm_kernel(
    const float* __restrict__ A, const float* __restrict__ Bm,
    const float* __restrict__ bias, float* __restrict__ C,
    int M, int N, int K, int lda, int ldb, int ldc)
{
    const int tile_m = blockIdx.y * 64, tile_n = blockIdx.x * 64;
    __shared__ float As[16][64];
    __shared__ float Bs[16][64];
    const int tid = threadIdx.x;
    const int tx = tid & 15, ty = tid >> 4;
    float acc[4][4] = {};
    for (int k0 = 0; k0 < K; k0 += 16) {
        {
            const int row = tid >> 2, kc = (tid & 3) * 4, gm = tile_m + row;
            #pragma unroll
            for (int i = 0; i < 4; ++i) {
                const int gk = k0 + kc + i;
                float v = 0.f;
                if (gm < M && gk < K) v = A[(long long)gm * lda + gk];
                As[kc + i][row] = v;
            }
        }
        {
            const int row = tid >> 2, kc = (tid & 3) * 4, gn = tile_n + row;
            #pragma unroll
            for (int i = 0; i < 4; ++i) {
                const int gk = k0 + kc + i;
                float v = 0.f;
                if (gn < N && gk < K) v = Bm[(long long)gn * ldb + gk];
                Bs[kc + i][row] = v;
            }
        }
        __syncthreads();
        #pragma unroll
        for (int kk = 0; kk < 16; ++kk) {
            float a[4], bb[4];
            #pragma unroll
            for (int i = 0; i < 4; ++i) a[i] = As[kk][ty * 4 + i];
            #pragma unroll
            for (int j = 0; j < 4; ++j) bb[j] = Bs[kk][tx * 4 + j];
            #pragma unroll
            for (int i = 0; i < 4; ++i)
                #pragma unroll
                for (int j = 0; j < 4; ++j)
                    acc[i][j] += a[i] * bb[j];
        }
        __syncthreads();
    }
    #pragma unroll
    for (int i = 0; i < 4; ++i) {
        const int gm = tile_m + ty * 4 + i;
        if (gm >= M) continue;
        #pragma unroll
        for (int j = 0; j < 4; ++j) {
            const int gn = tile_n + tx * 4 + j;
            if (gn >= N) continue;
            float v = acc[i][j];
            if (BIAS) v += bias[gn];
            C[(long long)gm * ldc + gn] = v;
        }
    }
}

// ================= LayerNorm JVP =================
__device__ __forceinline__ float blk_sum4(float v, float* smem) {
    #pragma unroll
    for (int off = 32; off > 0; off >>= 1) v += __shfl_down(v, off);
    __syncthreads();
    if ((threadIdx.x & 63) == 0) smem[threadIdx.x >> 6] = v;
    __syncthreads();
    return smem[0] + smem[1] + smem[2] + smem[3];
}

template<bool WF32>
__global__ __launch_bounds__(256) void ln_jvp_kernel(
    const float* __restrict__ z, const float* __restrict__ dz,
    const float* __restrict__ g, const float* __restrict__ b,
    float* __restrict__ y, float* __restrict__ dy,
    short* __restrict__ ybf, short* __restrict__ dybf)
{
    const long long row = blockIdx.x;
    const float* xr  = z  + row * D_;
    const float* dxr = dz + row * D_;
    __shared__ float smem[4];
    const int t = threadIdx.x;
    float x[3], dx[3];
    #pragma unroll
    for (int i = 0; i < 3; ++i) { x[i] = xr[t + 256 * i]; dx[i] = dxr[t + 256 * i]; }
    float sx  = blk_sum4(x[0] + x[1] + x[2], smem);
    float sdx = blk_sum4(dx[0] + dx[1] + dx[2], smem);
    const float mu = sx / D_, dmu = sdx / D_;
    float sv = 0.f, sc = 0.f;
    #pragma unroll
    for (int i = 0; i < 3; ++i) {
        const float xc = x[i] - mu;
        sv += xc * xc;
        sc += xc * (dx[i] - dmu);
    }
    sv = blk_sum4(sv, smem);
    sc = blk_sum4(sc, smem);
    const float rstd = rsqrtf(sv / D_ + 1e-6f);
    const float k2   = (sc / D_) * rstd * rstd;
    #pragma unroll
    for (int i = 0; i < 3; ++i) {
        const int c = t + 256 * i;
        const float yh  = (x[i] - mu) * rstd;
        const float dyh = (dx[i] - dmu) * rstd - yh * k2;
        const float yv  = yh * g[c] + b[c];
        const float dyv = dyh * g[c];
        if (WF32) { y[row * D_ + c] = yv; dy[row * D_ + c] = dyv; }
        ybf[row * D_ + c]  = (short)f2bf(yv);
        dybf[row * D_ + c] = (short)f2bf(dyv);
    }
}

__global__ __launch_bounds__(256) void cast_bf16_kernel(
    const float* __restrict__ in, short* __restrict__ out, int n4)
{
    for (int i = blockIdx.x * blockDim.x + threadIdx.x; i < n4;
         i += gridDim.x * blockDim.x) {
        const float4 v = ((const float4*)in)[i];
        short o[4];
        o[0] = (short)f2bf(v.x); o[1] = (short)f2bf(v.y);
        o[2] = (short)f2bf(v.z); o[3] = (short)f2bf(v.w);
        *(short4*)&out[i * 4] = *(short4*)o;
    }
}

__global__ __launch_bounds__(256) void wcast_kernel(
    const float* __restrict__ qw, const float* __restrict__ ow,
    const float* __restrict__ f1, const float* __restrict__ f2,
    short* __restrict__ dq, short* __restrict__ dow,
    short* __restrict__ d1, short* __restrict__ d2)
{
    const int b1 = 442368;
    const int b2 = b1 + 147456;
    const int b3 = b2 + 589824;
    const int total = b3 + 589824;
    for (int i = blockIdx.x * blockDim.x + threadIdx.x; i < total;
         i += gridDim.x * blockDim.x) {
        const float* s; short* d; int j;
        if (i < b1)      { s = qw; d = dq;  j = i; }
        else if (i < b2) { s = ow; d = dow; j = i - b1; }
        else if (i < b3) { s = f1; d = d1;  j = i - b2; }
        else             { s = f2; d = d2;  j = i - b3; }
        const float4 v = ((const float4*)s)[j];
        short o[4];
        o[0] = (short)f2bf(v.x); o[1] = (short)f2bf(v.y);
        o[2] = (short)f2bf(v.z); o[3] = (short)f2bf(v.w);
        *(short4*)&d[j * 4] = *(short4*)o;
    }
}

__global__ __launch_bounds__(256) void im2col_kernel(
    const float* __restrict__ x, short* __restrict__ xp, int total)
{
    for (int i = blockIdx.x * blockDim.x + threadIdx.x; i < total;
         i += gridDim.x * blockDim.x) {
        const int k  = i % 768;
        const int m  = i / 768;
        const int gh = m % GP_;
        const int n  = m / GP_;
        const int q  = k & 15;
        const int p  = (k >> 4) & 15;
        const int c  = k >> 8;
        const int hc = gh % 14, gr = gh / 14;
        const int ir = gr * 16 + p, ic = hc * 16 + q;
        xp[i] = (short)f2bf(x[(((long long)n * 3 + c) * 224 + ir) * 224 + ic]);
    }
}

__global__ __launch_bounds__(256) void assemble_kernel(
    const float* __restrict__ tok, const float* __restrict__ dtok,
    float* __restrict__ z, float* __restrict__ dz,
    const float* __restrict__ cls, const float* __restrict__ pos, int total)
{
    for (int i = blockIdx.x * blockDim.x + threadIdx.x; i < total;
         i += gridDim.x * blockDim.x) {
        const int d = i % D_;
        const int s = (i / D_) % S_;
        const int n = i / (D_ * S_);
        if (s == 0) {
            z[i]  = cls[d] + pos[d];
            dz[i] = 0.f;
        } else {
            const long long ti = ((long long)n * GP_ + s - 1) * D_ + d;
            z[i]  = tok[ti]  + pos[s * D_ + d];
            dz[i] = dtok[ti];
        }
    }
}

// ================= host helpers =================
static inline void mgemm_pair(hipStream_t st, const short* Af, const short* At,
                              const short* Bm, const float* bias,
                              void* Cf, void* Ct, int Mhalf, int N, int K, int ldc,
                              int mode, bool hasbias)
{
    dim3 grid(N / 128, (Mhalf + 63) / 64);
    dim3 blk(256);
#define PK(MD_, BI) mfma_pair_kernel<MD_, BI><<<grid, blk, 0, st>>>(Af, At, Bm, bias, Cf, Ct, Mhalf, N, K, ldc)
    if (mode == 0) { if (hasbias) PK(0, true); else PK(0, false); }
    else if (mode == 1) { if (hasbias) PK(1, true); else PK(1, false); }
    else if (mode == 2) { if (hasbias) PK(2, true); else PK(2, false); }
    else { if (hasbias) PK(3, true); else PK(3, false); }
#undef PK
}

static inline void cast_bf(hipStream_t st, const float* in, short* out, long long n) {
    const int n4 = (int)(n / 4);
    int g = (n4 + 255) / 256; if (g > 4096) g = 4096;
    cast_bf16_kernel<<<g, 256, 0, st>>>(in, out, n4);
}

extern "C" void kernel_launch(void* const* d_in, const int* in_sizes, int n_in,
                              void* d_out, int out_size, void* d_ws, size_t ws_size,
                              hipStream_t stream)
{
    const float* x       = (const float*)d_in[0];
    const float* tangent = (const float*)d_in[1];
    const float* conv_w  = (const float*)d_in[2];
    const float* conv_b  = (const float*)d_in[3];
    const float* cls     = (const float*)d_in[4];
    const float* pos     = (const float*)d_in[5];
    const float* ln1_g   = (const float*)d_in[6];
    const float* ln1_b   = (const float*)d_in[7];
    const float* qkv_w   = (const float*)d_in[8];
    const float* qkv_b   = (const float*)d_in[9];
    const float* out_w   = (const float*)d_in[10];
    const float* out_b   = (const float*)d_in[11];
    const float* ln2_g   = (const float*)d_in[12];
    const float* ln2_b   = (const float*)d_in[13];
    const float* fc1_w   = (const float*)d_in[14];
    const float* fc1_b   = (const float*)d_in[15];
    const float* fc2_w   = (const float*)d_in[16];
    const float* fc2_b   = (const float*)d_in[17];
    const float* lnf_g   = (const float*)d_in[18];
    const float* lnf_b   = (const float*)d_in[19];
    const float* head_w  = (const float*)d_in[20];
    const float* head_b  = (const float*)d_in[21];
    float* out = (float*)d_out;

    const int nBS = B_ * S_;
    const int NB = B_ * H_;
    const long long SD = (long long)S_ * D_;
    const long long PZ = (long long)MP_ * D_;
    const long long PQ = (long long)MP_ * 2304;
    const long long PH = (long long)MP_ * MD_;
    const long long PTOK = (long long)B_ * GP_ * D_;

    float* f = (float*)d_ws;
    float* z     = f;
    float* dz    = z + PZ;
    float* tok   = dz + PZ;
    float* dtok  = tok + PTOK;
    float* yf    = tok;
    float* dyf   = tok + PZ;

    short* sh     = (short*)(tok + 2 * PZ);
    short* ybf    = sh;
    short* dybf   = ybf + PZ;
    short* qkvbf  = dybf + PZ;
    short* dqkvbf = qkvbf + PQ;
    short* Vt     = dqkvbf + PQ;
    short* dVt    = Vt + (long long)NB * 64 * KP_;
    short* hbf    = dVt + (long long)NB * 64 * KP_;
    short* dhbf   = hbf + PH;
    short* xpbf   = hbf;
    short* dxpbf  = hbf + PTOK;
    short* wq     = dhbf + PH;
    short* wo     = wq + 2304 * 768;
    short* w1     = wo + 768 * 768;
    short* w2     = w1 + 3072 * 768;
    short* cwbf   = w2 + 768 * 3072;

    // ---- patch embedding ----
    {
        const int total = (int)PTOK;
        im2col_kernel<<<8192, 256, 0, stream>>>(x, xpbf, total);
        im2col_kernel<<<8192, 256, 0, stream>>>(tangent, dxpbf, total);
        cast_bf(stream, conv_w, cwbf, 768 * 768);
        mgemm_pair(stream, xpbf, dxpbf, cwbf, conv_b, tok, dtok,
                   B_ * GP_, D_, D_, D_, 0, true);
        const int tz = (int)(B_ * SD);
        assemble_kernel<<<8192, 256, 0, stream>>>(tok, dtok, z, dz, cls, pos, tz);
    }

    for (int l = 0; l < L_; ++l) {
        const float* l1g = ln1_g + (long long)l * D_;
        const float* l1b = ln1_b + (long long)l * D_;
        const float* qb  = qkv_b + (long long)l * 3 * D_;
        const float* ob  = out_b + (long long)l * D_;
        const float* l2g = ln2_g + (long long)l * D_;
        const float* l2b = ln2_b + (long long)l * D_;
        const float* f1b = fc1_b + (long long)l * MD_;
        const float* f2b = fc2_b + (long long)l * D_;

        wcast_kernel<<<4096, 256, 0, stream>>>(
            qkv_w + (long long)l * 3 * D_ * D_, out_w + (long long)l * D_ * D_,
            fc1_w + (long long)l * MD_ * D_,    fc2_w + (long long)l * D_ * MD_,
            wq, wo, w1, w2);

        // LN1
        ln_jvp_kernel<false><<<nBS, 256, 0, stream>>>(z, dz, l1g, l1b, nullptr, nullptr, ybf, dybf);
        // QKV (pair, bf16 out, staged epilogue)
        mgemm_pair(stream, ybf, dybf, wq, qb, qkvbf, dqkvbf,
                   nBS, 3 * D_, D_, 3 * D_, 2, true);

        // attention
        vtrans_kernel<<<NB * 4, 256, 0, stream>>>(qkvbf, dqkvbf, Vt, dVt);
        attn_fused_kernel<<<dim3(4, NB), 256, 0, stream>>>(qkvbf, dqkvbf, Vt, dVt, ybf, dybf);

        // projection + residual (pair, staged fp32 ACC)
        mgemm_pair(stream, ybf, dybf, wo, ob, z, dz, nBS, D_, D_, D_, 1, true);

        // LN2 + MLP: FC1 with fused GELU-JVP (staged epilogue), FC2 staged ACC
        ln_jvp_kernel<false><<<nBS, 256, 0, stream>>>(z, dz, l2g, l2b, nullptr, nullptr, ybf, dybf);
        mgemm_pair(stream, ybf, dybf, w1, f1b, hbf, dhbf, nBS, MD_, D_, MD_, 3, true);
        mgemm_pair(stream, hbf, dhbf, w2, f2b, z, dz, nBS, D_, MD_, D_, 1, true);
    }

    // final LN + head
    ln_jvp_kernel<true><<<nBS, 256, 0, stream>>>(z, dz, lnf_g, lnf_b, yf, dyf, ybf, dybf);
    gemm_kernel<true><<<dim3((NC_ + 63) / 64, 1), 256, 0, stream>>>(
        yf,  head_w, head_b, out,            B_, NC_, D_, (int)SD, D_, NC_);
    gemm_kernel<false><<<dim3((NC_ + 63) / 64, 1), 256, 0, stream>>>(
        dyf, head_w, nullptr, out + B_ * NC_, B_, NC_, D_, (int)SD, D_, NC_);
}

// Round 18
// 4482.836 us; speedup vs baseline: 1.1231x; 1.1231x over previous
//
// ViT-Base/16 fwd + JVP — Round 17: exact revert to R15 (best: 4511 us).
// Pair GEMM 64x128 (256 thr, 4 waves), staged epilogues (bf16 + fp32-ACC RMW),
// fast tanh-GELU, fused attention JVP, XCD swizzle.
#include <hip/hip_runtime.h>
#include <math.h>

static constexpr int B_   = 32;
static constexpr int S_   = 197;
static constexpr int D_   = 768;
static constexpr int H_   = 12;
static constexpr int L_   = 12;
static constexpr int MD_  = 3072;
static constexpr int NC_  = 1000;
static constexpr int GP_  = 196;
static constexpr int KP_  = 224;
static constexpr int MP_  = 6400;
static constexpr int EPAD = 136;   // staged bf16 epilogue LDS row stride (shorts)

typedef __attribute__((ext_vector_type(8))) short bf16x8v;
typedef __attribute__((ext_vector_type(4))) float f32x4v;

__device__ __forceinline__ unsigned short f2bf(float x) {
    union { float f; unsigned u; } v; v.f = x;
    unsigned r = v.u + 0x7fffu + ((v.u >> 16) & 1u);   // RNE
    return (unsigned short)(r >> 16);
}

// fast tanh-form GELU + derivative (|err| vs exact erf-GELU ~3e-4)
__device__ __forceinline__ void gelu_pair(float u, float& val, float& dcoef) {
    const float u2 = u * u;
    const float inner = 0.7978845608028654f * u * (1.f + 0.044715f * u2);
    const float e2 = __expf(2.f * inner);
    const float t = 1.f - 2.f * __builtin_amdgcn_rcpf(e2 + 1.f);
    val = 0.5f * u * (1.f + t);
    const float dinner = 0.7978845608028654f * (1.f + 0.134145f * u2);
    dcoef = 0.5f * (1.f + t) + 0.5f * u * (1.f - t * t) * dinner;
}

#define GLOAD_LDS16(gptr, lptr) \
    __builtin_amdgcn_global_load_lds((const __attribute__((address_space(1))) void*)(gptr), \
        (__attribute__((address_space(3))) void*)(lptr), 16, 0, 0)

__device__ __forceinline__ void xcd_swizzle(int& bx, int& by) {
    const int gx = gridDim.x, nwg = gx * gridDim.y;
    const int flat = blockIdx.y * gx + blockIdx.x;
    const int q = nwg >> 3, r = nwg & 7;
    const int xcd = flat & 7, idx = flat >> 3;
    const int nf = (xcd < r ? xcd * (q + 1) : r * (q + 1) + (xcd - r) * q) + idx;
    bx = nf % gx; by = nf / gx;
}

// ============ paired MFMA GEMM: 64x128 block tile, 4 waves (2x2), wave 32x64 ============
// MODE: 0 fp32 store, 1 fp32 ACC (staged coalesced RMW), 2 bf16 store, 3 GELU-JVP -> bf16.
template<int MODE, bool BIAS>
__global__ __launch_bounds__(256, 4) void mfma_pair_kernel(
    const short* __restrict__ Af, const short* __restrict__ At,
    const short* __restrict__ Bm, const float* __restrict__ bias,
    void* __restrict__ Cfv, void* __restrict__ Ctv,
    int Mhalf, int N, int K, int ldc)
{
    int bx, by; xcd_swizzle(bx, by);
    __shared__ __align__(16) short lds[16384];   // 32 KB
    const int tid  = threadIdx.x;
    const int lane = tid & 63;
    const int w    = tid >> 6;
    const int m0 = by * 64, n0 = bx * 128;
    const int wr = w >> 1, wc = w & 1;
    f32x4v accf[2][4] = {}, acct[2][4] = {};

    const int r_in = lane >> 2;
    const int cdst = lane & 3;
    const int sa = w * 16 + r_in;
    const int csa = cdst ^ ((sa >> 1) & 3);
    const size_t aoff = (size_t)(m0 + sa) * K + csa * 8;
    const int sb0 = w * 32 + r_in;
    const int sb1 = w * 32 + 16 + r_in;
    const int csb0 = cdst ^ ((sb0 >> 1) & 3);
    const int csb1 = cdst ^ ((sb1 >> 1) & 3);
    const size_t boff0 = (size_t)(n0 + sb0) * K + csb0 * 8;
    const size_t boff1 = (size_t)(n0 + sb1) * K + csb1 * 8;

#define LAF(b) (&lds[(b) * 2048])
#define LAT(b) (&lds[4096 + (b) * 2048])
#define LBB(b) (&lds[8192 + (b) * 4096])
#define STAGE(buf, koff) do {                                         \
        GLOAD_LDS16(Af + aoff  + (koff), LAF(buf) + w * 512);         \
        GLOAD_LDS16(At + aoff  + (koff), LAT(buf) + w * 512);         \
        GLOAD_LDS16(Bm + boff0 + (koff), LBB(buf) + w * 1024);        \
        GLOAD_LDS16(Bm + boff1 + (koff), LBB(buf) + w * 1024 + 512);  \
    } while (0)

    STAGE(0, 0);
    __syncthreads();

    const int NSTEP = K >> 5;
    int cur = 0;
    for (int k = 0; k < NSTEP; ++k) {
        const int nxt = cur ^ 1;
        if (k + 1 < NSTEP) STAGE(nxt, (size_t)(k + 1) * 32);
        bf16x8v af[2], at[2], bfr[4];
        #pragma unroll
        for (int m = 0; m < 2; ++m) {
            const int row = wr * 32 + m * 16 + (lane & 15);
            const int c = (lane >> 4) ^ ((row >> 1) & 3);
            af[m] = *(const bf16x8v*)(LAF(cur) + row * 32 + c * 8);
            at[m] = *(const bf16x8v*)(LAT(cur) + row * 32 + c * 8);
        }
        #pragma unroll
        for (int n = 0; n < 4; ++n) {
            const int row = wc * 64 + n * 16 + (lane & 15);
            const int c = (lane >> 4) ^ ((row >> 1) & 3);
            bfr[n] = *(const bf16x8v*)(LBB(cur) + row * 32 + c * 8);
        }
        #pragma unroll
        for (int m = 0; m < 2; ++m)
            #pragma unroll
            for (int n = 0; n < 4; ++n) {
                accf[m][n] = __builtin_amdgcn_mfma_f32_16x16x32_bf16(af[m], bfr[n], accf[m][n], 0, 0, 0);
                acct[m][n] = __builtin_amdgcn_mfma_f32_16x16x32_bf16(at[m], bfr[n], acct[m][n], 0, 0, 0);
            }
        __syncthreads();
        cur = nxt;
    }
#undef STAGE
#undef LAF
#undef LAT
#undef LBB

    const int g2 = lane >> 4, kc = lane & 15;
    if (MODE == 0) {
        const int col_base = n0 + wc * 64 + kc;
        const int row_base = m0 + wr * 32 + g2 * 4;
        #pragma unroll
        for (int n = 0; n < 4; ++n) {
            const int col = col_base + n * 16;
            const float bv = BIAS ? bias[col] : 0.f;
            #pragma unroll
            for (int m = 0; m < 2; ++m) {
                const int row = row_base + m * 16;
                #pragma unroll
                for (int r = 0; r < 4; ++r) {
                    if (row + r < Mhalf) {
                        const size_t off = (size_t)(row + r) * ldc + col;
                        ((float*)Cfv)[off] = accf[m][n][r] + bv;
                        ((float*)Ctv)[off] = acct[m][n][r];
                    }
                }
            }
        }
    } else if (MODE == 1) {
        // staged fp32 ACC: LDS [64][128] with col-XOR swizzle, coalesced float4 RMW
        float* lf = (float*)lds;
        #pragma unroll
        for (int half = 0; half < 2; ++half) {
            #pragma unroll
            for (int n = 0; n < 4; ++n) {
                const int col = wc * 64 + n * 16 + kc;
                const float bv = BIAS ? bias[n0 + col] : 0.f;
                #pragma unroll
                for (int m = 0; m < 2; ++m) {
                    #pragma unroll
                    for (int r = 0; r < 4; ++r) {
                        const int row = wr * 32 + m * 16 + g2 * 4 + r;
                        const int swz = ((row >> 2) & 3) << 4;
                        lf[row * 128 + (col ^ swz)] =
                            half == 0 ? (accf[m][n][r] + bv) : acct[m][n][r];
                    }
                }
            }
            __syncthreads();
            float* dst = (float*)(half == 0 ? Cfv : Ctv);
            #pragma unroll
            for (int it = 0; it < 4; ++it) {
                const int row = it * 16 + (tid >> 4);
                const int grow = m0 + row;
                const int swz = ((row >> 2) & 3) << 4;
                if (grow < Mhalf) {
                    #pragma unroll
                    for (int q = 0; q < 2; ++q) {
                        const int c4 = (tid & 15) * 8 + q * 4;
                        float* gp = dst + (size_t)grow * ldc + n0 + c4;
                        float4 g = *(float4*)gp;
                        const float4 s = *(const float4*)&lf[row * 128 + (c4 ^ swz)];
                        g.x += s.x; g.y += s.y; g.z += s.z; g.w += s.w;
                        *(float4*)gp = g;
                    }
                }
            }
            __syncthreads();
        }
    } else {
        // staged bf16 epilogue (stride EPAD), coalesced flush
        #pragma unroll
        for (int half = 0; half < 2; ++half) {
            #pragma unroll
            for (int n = 0; n < 4; ++n) {
                const int col = wc * 64 + n * 16 + kc;
                const float bv = BIAS ? bias[n0 + col] : 0.f;
                #pragma unroll
                for (int m = 0; m < 2; ++m) {
                    #pragma unroll
                    for (int r = 0; r < 4; ++r) {
                        const int row = wr * 32 + m * 16 + g2 * 4 + r;
                        const float vf = accf[m][n][r] + bv;
                        float outv;
                        if (MODE == 2) {
                            outv = half == 0 ? vf : acct[m][n][r];
                        } else {
                            float gv, gd;
                            gelu_pair(vf, gv, gd);
                            outv = half == 0 ? gv : acct[m][n][r] * gd;
                        }
                        lds[row * EPAD + col] = (short)f2bf(outv);
                    }
                }
            }
            __syncthreads();
            short* dst = (short*)(half == 0 ? Cfv : Ctv);
            #pragma unroll
            for (int it = 0; it < 4; ++it) {
                const int row = it * 16 + (tid >> 4);
                const int grow = m0 + row;
                if (grow < Mhalf) {
                    *(bf16x8v*)(dst + (size_t)grow * ldc + n0 + (tid & 15) * 8)
                        = *(const bf16x8v*)&lds[row * EPAD + (tid & 15) * 8];
                }
            }
            __syncthreads();
        }
    }
}

// ================= fully fused attention JVP =================
__global__ __launch_bounds__(256) void attn_fused_kernel(
    const short* __restrict__ qkvb, const short* __restrict__ dqkvb,
    const short* __restrict__ Vtb_, const short* __restrict__ dVtb_,
    short* __restrict__ obf, short* __restrict__ dobf)
{
    const int qt = blockIdx.x;
    const int b  = blockIdx.y;
    const int n = b / H_, h = b - n * H_;
    const short* qb  = qkvb  + (size_t)n * S_ * 2304 + h * 64;
    const short* kb  = qb + 768;
    const short* dqb = dqkvb + (size_t)n * S_ * 2304 + h * 64;
    const short* dkb = dqb + 768;
    const short* Vb  = Vtb_  + (size_t)b * 64 * KP_;
    const short* dVb = dVtb_ + (size_t)b * 64 * KP_;

    __shared__ __align__(16) short lds[32768];
    const int tid = threadIdx.x, lane = tid & 63, w = tid >> 6;
    const int g = lane >> 4, kc = lane & 15;
    const int srow = lane >> 2, cdst = lane & 3;
    const int csrc = cdst ^ ((srow >> 1) & 3);

    {
        const size_t qr = (size_t)min(qt * 64 + w * 16 + srow, S_ - 1) * 2304;
        #pragma unroll
        for (int kw = 0; kw < 2; ++kw) {
            GLOAD_LDS16(qb  + qr + kw * 32 + csrc * 8, &lds[w * 1024 + kw * 512]);
            GLOAD_LDS16(dqb + qr + kw * 32 + csrc * 8, &lds[4096 + w * 1024 + kw * 512]);
        }
    }

    f32x4v aS[14], aD[14];
    #pragma unroll
    for (int i = 0; i < 14; ++i) { aS[i] = (f32x4v){0,0,0,0}; aD[i] = (f32x4v){0,0,0,0}; }
    bf16x8v qf[2], dqf[2];

    #pragma unroll
    for (int kt = 0; kt < 7; ++kt) {
        {
            const int kwin = w & 1;
            const short* src = (w < 2) ? kb : dkb;
            const int base = (w < 2) ? 8192 : 10240;
            #pragma unroll
            for (int half = 0; half < 2; ++half) {
                const size_t kr = (size_t)min(kt * 32 + half * 16 + srow, S_ - 1) * 2304;
                GLOAD_LDS16(src + kr + kwin * 32 + csrc * 8,
                            &lds[base + kwin * 1024 + half * 512]);
            }
        }
        __syncthreads();
        if (kt == 0) {
            #pragma unroll
            for (int kw = 0; kw < 2; ++kw) {
                const int c = g ^ ((kc >> 1) & 3);
                qf[kw]  = *(const bf16x8v*)&lds[w * 1024 + kw * 512 + kc * 32 + c * 8];
                dqf[kw] = *(const bf16x8v*)&lds[4096 + w * 1024 + kw * 512 + kc * 32 + c * 8];
            }
        }
        #pragma unroll
        for (int nf = 0; nf < 2; ++nf) {
            const int row = nf * 16 + kc;
            const int c = g ^ ((row >> 1) & 3);
            const bf16x8v kf0  = *(const bf16x8v*)&lds[8192  + row * 32 + c * 8];
            const bf16x8v kf1  = *(const bf16x8v*)&lds[8192  + 1024 + row * 32 + c * 8];
            const bf16x8v dkf0 = *(const bf16x8v*)&lds[10240 + row * 32 + c * 8];
            const bf16x8v dkf1 = *(const bf16x8v*)&lds[10240 + 1024 + row * 32 + c * 8];
            const int fi = kt * 2 + nf;
            aS[fi] = __builtin_amdgcn_mfma_f32_16x16x32_bf16(qf[0], kf0, aS[fi], 0,0,0);
            aS[fi] = __builtin_amdgcn_mfma_f32_16x16x32_bf16(qf[1], kf1, aS[fi], 0,0,0);
            aD[fi] = __builtin_amdgcn_mfma_f32_16x16x32_bf16(dqf[0], kf0, aD[fi], 0,0,0);
            aD[fi] = __builtin_amdgcn_mfma_f32_16x16x32_bf16(dqf[1], kf1, aD[fi], 0,0,0);
            aD[fi] = __builtin_amdgcn_mfma_f32_16x16x32_bf16(qf[0], dkf0, aD[fi], 0,0,0);
            aD[fi] = __builtin_amdgcn_mfma_f32_16x16x32_bf16(qf[1], dkf1, aD[fi], 0,0,0);
        }
        __syncthreads();
    }

    float pm[4] = {-3.0e38f, -3.0e38f, -3.0e38f, -3.0e38f};
    #pragma unroll
    for (int fi = 0; fi < 14; ++fi) {
        if (fi * 16 + kc < S_) {
            #pragma unroll
            for (int r = 0; r < 4; ++r) pm[r] = fmaxf(pm[r], aS[fi][r]);
        }
    }
    #pragma unroll
    for (int off = 1; off < 16; off <<= 1)
        #pragma unroll
        for (int r = 0; r < 4; ++r) pm[r] = fmaxf(pm[r], __shfl_xor(pm[r], off));

    float den[4] = {0,0,0,0}, tsm[4] = {0,0,0,0};
    #pragma unroll
    for (int fi = 0; fi < 14; ++fi) {
        const bool val = fi * 16 + kc < S_;
        #pragma unroll
        for (int r = 0; r < 4; ++r) {
            const float s  = aS[fi][r] * 0.125f;
            const float ds = aD[fi][r] * 0.125f;
            const float e = val ? __expf(s - pm[r] * 0.125f) : 0.f;
            den[r] += e; tsm[r] += e * ds;
            aS[fi][r] = e; aD[fi][r] = ds;
        }
    }
    #pragma unroll
    for (int off = 1; off < 16; off <<= 1)
        #pragma unroll
        for (int r = 0; r < 4; ++r) {
            den[r] += __shfl_xor(den[r], off);
            tsm[r] += __shfl_xor(tsm[r], off);
        }
    float inv[4], tq[4];
    #pragma unroll
    for (int r = 0; r < 4; ++r) { inv[r] = 1.f / den[r]; tq[r] = tsm[r] * inv[r]; }

    const int lpw = w * 3584, ldpw = 14336 + w * 3584;
    #pragma unroll
    for (int fi = 0; fi < 14; ++fi) {
        const int kwin = fi >> 1;
        const int chunkbase = (fi & 1) * 2 + (kc >> 3);
        #pragma unroll
        for (int r = 0; r < 4; ++r) {
            const int qs = g * 4 + r;
            const int swz = chunkbase ^ ((qs >> 1) & 3);
            const int addr = kwin * 512 + qs * 32 + swz * 8 + (kc & 7);
            const float p  = aS[fi][r] * inv[r];
            const float dp = p * (aD[fi][r] - tq[r]);
            lds[lpw  + addr] = (short)f2bf(p);
            lds[ldpw + addr] = (short)f2bf(dp);
        }
    }

    f32x4v aO[4], aDO[4];
    #pragma unroll
    for (int i = 0; i < 4; ++i) { aO[i] = (f32x4v){0,0,0,0}; aDO[i] = (f32x4v){0,0,0,0}; }

    #pragma unroll
    for (int kt = 0; kt < 7; ++kt) {
        {
            const size_t vr = (size_t)(w * 16 + srow) * KP_ + kt * 32 + csrc * 8;
            GLOAD_LDS16(Vb  + vr, &lds[28672 + w * 512]);
            GLOAD_LDS16(dVb + vr, &lds[30720 + w * 512]);
        }
        __syncthreads();
        bf16x8v pa, dpa;
        {
            const int c = g ^ ((kc >> 1) & 3);
            pa  = *(const bf16x8v*)&lds[lpw  + kt * 512 + kc * 32 + c * 8];
            dpa = *(const bf16x8v*)&lds[ldpw + kt * 512 + kc * 32 + c * 8];
        }
        #pragma unroll
        for (int nf = 0; nf < 4; ++nf) {
            const int row = nf * 16 + kc;
            const int c = (g) ^ ((row >> 1) & 3);
            const bf16x8v vf  = *(const bf16x8v*)&lds[28672 + row * 32 + c * 8];
            const bf16x8v dvf = *(const bf16x8v*)&lds[30720 + row * 32 + c * 8];
            aO[nf]  = __builtin_amdgcn_mfma_f32_16x16x32_bf16(pa,  vf,  aO[nf], 0,0,0);
            aDO[nf] = __builtin_amdgcn_mfma_f32_16x16x32_bf16(dpa, vf,  aDO[nf], 0,0,0);
            aDO[nf] = __builtin_amdgcn_mfma_f32_16x16x32_bf16(pa,  dvf, aDO[nf], 0,0,0);
        }
        __syncthreads();
    }

    short* ob  = obf  + (size_t)n * S_ * D_ + h * 64;
    short* dob = dobf + (size_t)n * S_ * D_ + h * 64;
    #pragma unroll
    for (int nf = 0; nf < 4; ++nf) {
        const int dh = nf * 16 + kc;
        #pragma unroll
        for (int r = 0; r < 4; ++r) {
            const int q = qt * 64 + w * 16 + g * 4 + r;
            if (q < S_) {
                ob [(size_t)q * D_ + dh] = (short)f2bf(aO[nf][r]);
                dob[(size_t)q * D_ + dh] = (short)f2bf(aDO[nf][r]);
            }
        }
    }
}

// ================= V transpose =================
__global__ __launch_bounds__(256) void vtrans_kernel(
    const short* __restrict__ qkvb, const short* __restrict__ dqkvb,
    short* __restrict__ Vt, short* __restrict__ dVt)
{
    const int blk = blockIdx.x;
    const int b = blk >> 2, kt = blk & 3;
    const int n = b / H_, h = b - n * H_;
    const short* vb  = qkvb  + (size_t)n * S_ * 2304 + 1536 + h * 64;
    const short* dvb = dqkvb + (size_t)n * S_ * 2304 + 1536 + h * 64;
    __shared__ short t1[64][65], t2[64][65];
    const int tid = threadIdx.x;
    #pragma unroll
    for (int j = 0; j < 16; ++j) {
        const int e = tid + 256 * j;
        const int kk = e >> 6, dh = e & 63;
        const int gk = kt * 64 + kk;
        short v = 0, dv = 0;
        if (gk < S_) { v = vb[(size_t)gk * 2304 + dh]; dv = dvb[(size_t)gk * 2304 + dh]; }
        t1[dh][kk] = v; t2[dh][kk] = dv;
    }
    __syncthreads();
    #pragma unroll
    for (int j = 0; j < 16; ++j) {
        const int e = tid + 256 * j;
        const int dh = e >> 6, kk = e & 63;
        const int ok = kt * 64 + kk;
        if (ok < KP_) {
            Vt [(size_t)b * 64 * KP_ + (size_t)dh * KP_ + ok] = t1[dh][kk];
            dVt[(size_t)b * 64 * KP_ + (size_t)dh * KP_ + ok] = t2[dh][kk];
        }
    }
}

// ================= fp32 GEMM (head only) =================
template<bool BIAS>
__global__ __launch_bounds__(256) void gemm_kernel(
    const float* __restrict__ A, const float* __restrict__ Bm,
    const float* __restrict__ bias, float* __restrict__ C,
    int M, int N, int K, int lda, int ldb, int ldc)
{
    const int tile_m = blockIdx.y * 64, tile_n = blockIdx.x * 64;
    __shared__ float As[16][64];
    __shared__ float Bs[16][64];
    const int tid = threadIdx.x;
    const int tx = tid & 15, ty = tid >> 4;
    float acc[4][4] = {};
    for (int k0 = 0; k0 < K; k0 += 16) {
        {
            const int row = tid >> 2, kc = (tid & 3) * 4, gm = tile_m + row;
            #pragma unroll
            for (int i = 0; i < 4; ++i) {
                const int gk = k0 + kc + i;
                float v = 0.f;
                if (gm < M && gk < K) v = A[(long long)gm * lda + gk];
                As[kc + i][row] = v;
            }
        }
        {
            const int row = tid >> 2, kc = (tid & 3) * 4, gn = tile_n + row;
            #pragma unroll
            for (int i = 0; i < 4; ++i) {
                const int gk = k0 + kc + i;
                float v = 0.f;
                if (gn < N && gk < K) v = Bm[(long long)gn * ldb + gk];
                Bs[kc + i][row] = v;
            }
        }
        __syncthreads();
        #pragma unroll
        for (int kk = 0; kk < 16; ++kk) {
            float a[4], bb[4];
            #pragma unroll
            for (int i = 0; i < 4; ++i) a[i] = As[kk][ty * 4 + i];
            #pragma unroll
            for (int j = 0; j < 4; ++j) bb[j] = Bs[kk][tx * 4 + j];
            #pragma unroll
            for (int i = 0; i < 4; ++i)
                #pragma unroll
                for (int j = 0; j < 4; ++j)
                    acc[i][j] += a[i] * bb[j];
        }
        __syncthreads();
    }
    #pragma unroll
    for (int i = 0; i < 4; ++i) {
        const int gm = tile_m + ty * 4 + i;
        if (gm >= M) continue;
        #pragma unroll
        for (int j = 0; j < 4; ++j) {
            const int gn = tile_n + tx * 4 + j;
            if (gn >= N) continue;
            float v = acc[i][j];
            if (BIAS) v += bias[gn];
            C[(long long)gm * ldc + gn] = v;
        }
    }
}

// ================= LayerNorm JVP =================
__device__ __forceinline__ float blk_sum4(float v, float* smem) {
    #pragma unroll
    for (int off = 32; off > 0; off >>= 1) v += __shfl_down(v, off);
    __syncthreads();
    if ((threadIdx.x & 63) == 0) smem[threadIdx.x >> 6] = v;
    __syncthreads();
    return smem[0] + smem[1] + smem[2] + smem[3];
}

template<bool WF32>
__global__ __launch_bounds__(256) void ln_jvp_kernel(
    const float* __restrict__ z, const float* __restrict__ dz,
    const float* __restrict__ g, const float* __restrict__ b,
    float* __restrict__ y, float* __restrict__ dy,
    short* __restrict__ ybf, short* __restrict__ dybf)
{
    const long long row = blockIdx.x;
    const float* xr  = z  + row * D_;
    const float* dxr = dz + row * D_;
    __shared__ float smem[4];
    const int t = threadIdx.x;
    float x[3], dx[3];
    #pragma unroll
    for (int i = 0; i < 3; ++i) { x[i] = xr[t + 256 * i]; dx[i] = dxr[t + 256 * i]; }
    float sx  = blk_sum4(x[0] + x[1] + x[2], smem);
    float sdx = blk_sum4(dx[0] + dx[1] + dx[2], smem);
    const float mu = sx / D_, dmu = sdx / D_;
    float sv = 0.f, sc = 0.f;
    #pragma unroll
    for (int i = 0; i < 3; ++i) {
        const float xc = x[i] - mu;
        sv += xc * xc;
        sc += xc * (dx[i] - dmu);
    }
    sv = blk_sum4(sv, smem);
    sc = blk_sum4(sc, smem);
    const float rstd = rsqrtf(sv / D_ + 1e-6f);
    const float k2   = (sc / D_) * rstd * rstd;
    #pragma unroll
    for (int i = 0; i < 3; ++i) {
        const int c = t + 256 * i;
        const float yh  = (x[i] - mu) * rstd;
        const float dyh = (dx[i] - dmu) * rstd - yh * k2;
        const float yv  = yh * g[c] + b[c];
        const float dyv = dyh * g[c];
        if (WF32) { y[row * D_ + c] = yv; dy[row * D_ + c] = dyv; }
        ybf[row * D_ + c]  = (short)f2bf(yv);
        dybf[row * D_ + c] = (short)f2bf(dyv);
    }
}

__global__ __launch_bounds__(256) void cast_bf16_kernel(
    const float* __restrict__ in, short* __restrict__ out, int n4)
{
    for (int i = blockIdx.x * blockDim.x + threadIdx.x; i < n4;
         i += gridDim.x * blockDim.x) {
        const float4 v = ((const float4*)in)[i];
        short o[4];
        o[0] = (short)f2bf(v.x); o[1] = (short)f2bf(v.y);
        o[2] = (short)f2bf(v.z); o[3] = (short)f2bf(v.w);
        *(short4*)&out[i * 4] = *(short4*)o;
    }
}

__global__ __launch_bounds__(256) void wcast_kernel(
    const float* __restrict__ qw, const float* __restrict__ ow,
    const float* __restrict__ f1, const float* __restrict__ f2,
    short* __restrict__ dq, short* __restrict__ dow,
    short* __restrict__ d1, short* __restrict__ d2)
{
    const int b1 = 442368;
    const int b2 = b1 + 147456;
    const int b3 = b2 + 589824;
    const int total = b3 + 589824;
    for (int i = blockIdx.x * blockDim.x + threadIdx.x; i < total;
         i += gridDim.x * blockDim.x) {
        const float* s; short* d; int j;
        if (i < b1)      { s = qw; d = dq;  j = i; }
        else if (i < b2) { s = ow; d = dow; j = i - b1; }
        else if (i < b3) { s = f1; d = d1;  j = i - b2; }
        else             { s = f2; d = d2;  j = i - b3; }
        const float4 v = ((const float4*)s)[j];
        short o[4];
        o[0] = (short)f2bf(v.x); o[1] = (short)f2bf(v.y);
        o[2] = (short)f2bf(v.z); o[3] = (short)f2bf(v.w);
        *(short4*)&d[j * 4] = *(short4*)o;
    }
}

__global__ __launch_bounds__(256) void im2col_kernel(
    const float* __restrict__ x, short* __restrict__ xp, int total)
{
    for (int i = blockIdx.x * blockDim.x + threadIdx.x; i < total;
         i += gridDim.x * blockDim.x) {
        const int k  = i % 768;
        const int m  = i / 768;
        const int gh = m % GP_;
        const int n  = m / GP_;
        const int q  = k & 15;
        const int p  = (k >> 4) & 15;
        const int c  = k >> 8;
        const int hc = gh % 14, gr = gh / 14;
        const int ir = gr * 16 + p, ic = hc * 16 + q;
        xp[i] = (short)f2bf(x[(((long long)n * 3 + c) * 224 + ir) * 224 + ic]);
    }
}

__global__ __launch_bounds__(256) void assemble_kernel(
    const float* __restrict__ tok, const float* __restrict__ dtok,
    float* __restrict__ z, float* __restrict__ dz,
    const float* __restrict__ cls, const float* __restrict__ pos, int total)
{
    for (int i = blockIdx.x * blockDim.x + threadIdx.x; i < total;
         i += gridDim.x * blockDim.x) {
        const int d = i % D_;
        const int s = (i / D_) % S_;
        const int n = i / (D_ * S_);
        if (s == 0) {
            z[i]  = cls[d] + pos[d];
            dz[i] = 0.f;
        } else {
            const long long ti = ((long long)n * GP_ + s - 1) * D_ + d;
            z[i]  = tok[ti]  + pos[s * D_ + d];
            dz[i] = dtok[ti];
        }
    }
}

// ================= host helpers =================
static inline void mgemm_pair(hipStream_t st, const short* Af, const short* At,
                              const short* Bm, const float* bias,
                              void* Cf, void* Ct, int Mhalf, int N, int K, int ldc,
                              int mode, bool hasbias)
{
    dim3 grid(N / 128, (Mhalf + 63) / 64);
    dim3 blk(256);
#define PK(MD_, BI) mfma_pair_kernel<MD_, BI><<<grid, blk, 0, st>>>(Af, At, Bm, bias, Cf, Ct, Mhalf, N, K, ldc)
    if (mode == 0) { if (hasbias) PK(0, true); else PK(0, false); }
    else if (mode == 1) { if (hasbias) PK(1, true); else PK(1, false); }
    else if (mode == 2) { if (hasbias) PK(2, true); else PK(2, false); }
    else { if (hasbias) PK(3, true); else PK(3, false); }
#undef PK
}

static inline void cast_bf(hipStream_t st, const float* in, short* out, long long n) {
    const int n4 = (int)(n / 4);
    int g = (n4 + 255) / 256; if (g > 4096) g = 4096;
    cast_bf16_kernel<<<g, 256, 0, st>>>(in, out, n4);
}

extern "C" void kernel_launch(void* const* d_in, const int* in_sizes, int n_in,
                              void* d_out, int out_size, void* d_ws, size_t ws_size,
                              hipStream_t stream)
{
    const float* x       = (const float*)d_in[0];
    const float* tangent = (const float*)d_in[1];
    const float* conv_w  = (const float*)d_in[2];
    const float* conv_b  = (const float*)d_in[3];
    const float* cls     = (const float*)d_in[4];
    const float* pos     = (const float*)d_in[5];
    const float* ln1_g   = (const float*)d_in[6];
    const float* ln1_b   = (const float*)d_in[7];
    const float* qkv_w   = (const float*)d_in[8];
    const float* qkv_b   = (const float*)d_in[9];
    const float* out_w   = (const float*)d_in[10];
    const float* out_b   = (const float*)d_in[11];
    const float* ln2_g   = (const float*)d_in[12];
    const float* ln2_b   = (const float*)d_in[13];
    const float* fc1_w   = (const float*)d_in[14];
    const float* fc1_b   = (const float*)d_in[15];
    const float* fc2_w   = (const float*)d_in[16];
    const float* fc2_b   = (const float*)d_in[17];
    const float* lnf_g   = (const float*)d_in[18];
    const float* lnf_b   = (const float*)d_in[19];
    const float* head_w  = (const float*)d_in[20];
    const float* head_b  = (const float*)d_in[21];
    float* out = (float*)d_out;

    const int nBS = B_ * S_;
    const int NB = B_ * H_;
    const long long SD = (long long)S_ * D_;
    const long long PZ = (long long)MP_ * D_;
    const long long PQ = (long long)MP_ * 2304;
    const long long PH = (long long)MP_ * MD_;
    const long long PTOK = (long long)B_ * GP_ * D_;

    float* f = (float*)d_ws;
    float* z     = f;
    float* dz    = z + PZ;
    float* tok   = dz + PZ;
    float* dtok  = tok + PTOK;
    float* yf    = tok;
    float* dyf   = tok + PZ;

    short* sh     = (short*)(tok + 2 * PZ);
    short* ybf    = sh;
    short* dybf   = ybf + PZ;
    short* qkvbf  = dybf + PZ;
    short* dqkvbf = qkvbf + PQ;
    short* Vt     = dqkvbf + PQ;
    short* dVt    = Vt + (long long)NB * 64 * KP_;
    short* hbf    = dVt + (long long)NB * 64 * KP_;
    short* dhbf   = hbf + PH;
    short* xpbf   = hbf;
    short* dxpbf  = hbf + PTOK;
    short* wq     = dhbf + PH;
    short* wo     = wq + 2304 * 768;
    short* w1     = wo + 768 * 768;
    short* w2     = w1 + 3072 * 768;
    short* cwbf   = w2 + 768 * 3072;

    // ---- patch embedding ----
    {
        const int total = (int)PTOK;
        im2col_kernel<<<8192, 256, 0, stream>>>(x, xpbf, total);
        im2col_kernel<<<8192, 256, 0, stream>>>(tangent, dxpbf, total);
        cast_bf(stream, conv_w, cwbf, 768 * 768);
        mgemm_pair(stream, xpbf, dxpbf, cwbf, conv_b, tok, dtok,
                   B_ * GP_, D_, D_, D_, 0, true);
        const int tz = (int)(B_ * SD);
        assemble_kernel<<<8192, 256, 0, stream>>>(tok, dtok, z, dz, cls, pos, tz);
    }

    for (int l = 0; l < L_; ++l) {
        const float* l1g = ln1_g + (long long)l * D_;
        const float* l1b = ln1_b + (long long)l * D_;
        const float* qb  = qkv_b + (long long)l * 3 * D_;
        const float* ob  = out_b + (long long)l * D_;
        const float* l2g = ln2_g + (long long)l * D_;
        const float* l2b = ln2_b + (long long)l * D_;
        const float* f1b = fc1_b + (long long)l * MD_;
        const float* f2b = fc2_b + (long long)l * D_;

        wcast_kernel<<<4096, 256, 0, stream>>>(
            qkv_w + (long long)l * 3 * D_ * D_, out_w + (long long)l * D_ * D_,
            fc1_w + (long long)l * MD_ * D_,    fc2_w + (long long)l * D_ * MD_,
            wq, wo, w1, w2);

        // LN1
        ln_jvp_kernel<false><<<nBS, 256, 0, stream>>>(z, dz, l1g, l1b, nullptr, nullptr, ybf, dybf);
        // QKV (pair, bf16 out, staged epilogue)
        mgemm_pair(stream, ybf, dybf, wq, qb, qkvbf, dqkvbf,
                   nBS, 3 * D_, D_, 3 * D_, 2, true);

        // attention
        vtrans_kernel<<<NB * 4, 256, 0, stream>>>(qkvbf, dqkvbf, Vt, dVt);
        attn_fused_kernel<<<dim3(4, NB), 256, 0, stream>>>(qkvbf, dqkvbf, Vt, dVt, ybf, dybf);

        // projection + residual (pair, staged fp32 ACC)
        mgemm_pair(stream, ybf, dybf, wo, ob, z, dz, nBS, D_, D_, D_, 1, true);

        // LN2 + MLP: FC1 with fused GELU-JVP (staged epilogue), FC2 staged ACC
        ln_jvp_kernel<false><<<nBS, 256, 0, stream>>>(z, dz, l2g, l2b, nullptr, nullptr, ybf, dybf);
        mgemm_pair(stream, ybf, dybf, w1, f1b, hbf, dhbf, nBS, MD_, D_, MD_, 3, true);
        mgemm_pair(stream, hbf, dhbf, w2, f2b, z, dz, nBS, D_, MD_, D_, 1, true);
    }

    // final LN + head
    ln_jvp_kernel<true><<<nBS, 256, 0, stream>>>(z, dz, lnf_g, lnf_b, yf, dyf, ybf, dybf);
    gemm_kernel<true><<<dim3((NC_ + 63) / 64, 1), 256, 0, stream>>>(
        yf,  head_w, head_b, out,            B_, NC_, D_, (int)SD, D_, NC_);
    gemm_kernel<false><<<dim3((NC_ + 63) / 64, 1), 256, 0, stream>>>(
        dyf, head_w, nullptr, out + B_ * NC_, B_, NC_, D_, (int)SD, D_, NC_);
}